// Round 16
// baseline (449.904 us; speedup 1.0000x reference)
//
#include <hip/hip_runtime.h>

// IDWT2D db4, periodized. Input x: [64][256][256][16] f32 (cA|cH|cV|cD x 4ch),
// output: [64][512][512][4] f32.
//
// R15: 8-blocks-per-CU via 256-thread blocks, x-split tiles.
// Block = 16 j-rows x 64 j-cols (+3 redundant x-halo intermediate cols).
// Rationale: 512-thread blocks cap at 4 blocks/CU (32-wave cap); every
// barrier convoys 8 waves. 256-thread blocks give 8 independent 4-wave
// barrier-groups per CU -> much better cross-block phase overlap, finer
// dispatch tail. x-halo costs 3 cols (~5%) vs R12's y-halo mistake (+37%).
// Pass1: 134 threads (67 cols x 2 halves), paired dense 32B/lane global
// loads, 4-row register sliding window, prefetch 1 row ahead.
// Pass2: 256 threads = 1 output f4 each (p=t>>7, colf4=t&127), 8 LDS reads,
// dense f4 stores (128-f4 contiguous runs). LDS 8.6 KB double-buffered,
// lgkm-only barrier, pk-fma. __launch_bounds__(256,8) pins VGPR<=64.

#define N 256
#define RJ 16
#define W 64          // output column-pairs per block
#define HC (W + 3)    // intermediate columns incl. halo = 67

typedef float f32x4 __attribute__((ext_vector_type(4)));

// lgkm-only barrier: LDS producer-consumer sync without vmcnt drain.
#define LGKM_BARRIER()                                   \
  do {                                                   \
    asm volatile("s_waitcnt lgkmcnt(0)" ::: "memory");   \
    __builtin_amdgcn_s_barrier();                        \
    asm volatile("" ::: "memory");                       \
  } while (0)

__device__ __forceinline__ f32x4 fma4v(const f32x4 acc, const float s,
                                       const f32x4 a) {
  const f32x4 sv = {s, s, s, s};
  return __builtin_elementwise_fma(a, sv, acc);
}

__global__ __launch_bounds__(256, 8) void idwt2_sep15_kernel(
    const float* __restrict__ x, float* __restrict__ out) {
  constexpr float LO[8] = {
      0.23037781330885523f,  0.7148465705525415f,  0.6308807679295904f,
      -0.02798376941698385f, -0.18703481171888114f, 0.030841381835986965f,
      0.032883011666982945f, -0.010597401784997278f};
  constexpr float HIW[8] = {
      -0.010597401784997278f, -0.032883011666982945f, 0.030841381835986965f,
      0.18703481171888114f,  -0.02798376941698385f,  -0.6308807679295904f,
      0.7148465705525415f,   -0.23037781330885523f};
  const float Lw[2][4] = {{LO[6], LO[4], LO[2], LO[0]},
                          {LO[7], LO[5], LO[3], LO[1]}};
  const float Hw[2][4] = {{HIW[6], HIW[4], HIW[2], HIW[0]},
                          {HIW[7], HIW[5], HIW[3], HIW[1]}};

  // [buf][plane][col] f32x4; planes: 0=lo*p0, 1=lo*p1, 2=hi*p0, 3=hi*p1.
  __shared__ f32x4 I[2][4][HC];

  const int t = threadIdx.x;
  const int bx = blockIdx.x;
  // bx = b*64 + rowgroup*4 + colquarter  (colquarter fastest: x/y halo
  // sharers adjacent in dispatch order for L2/L3 reuse)
  const int cq = bx & 3;
  const int rg = (bx >> 2) & 15;
  const int b = bx >> 6;
  const int r0 = rg * RJ;
  const int jc0 = cq * W;

  const f32x4* xb4 = reinterpret_cast<const f32x4*>(x) + (size_t)b * N * N * 4;
  f32x4* ob = reinterpret_cast<f32x4*>(out) + (size_t)b * (2 * N) * (2 * N);

  // ---- Pass1 identity: slot t = (col c=t>>1, half h=t&1), t < 2*HC ----
  const bool doP1 = t < 2 * HC;
  const int c_ = t >> 1;
  const int sh = t & 1;  // 0: lo from (cA,cH); 1: hi from (cV,cD)
  const int scol = (jc0 + c_) & (N - 1);
  const f32x4* xcolp = xb4 + (size_t)scol * 4 + sh * 2;

  f32x4 wA[4], wB[4], nA, nB;
  auto ldrow = [&](int lr, f32x4& A, f32x4& B) {
    const int gr = (r0 + lr) & (N - 1);
    const f32x4* p = xcolp + (size_t)gr * (N * 4);
    A = p[0];
    B = p[1];
  };

  // y-filter local j-row j into I[buf]; window slot (j+sy)&3 holds row j+sy.
  auto p1 = [&](int j, int buf) {
    f32x4 v0 = {0.f, 0.f, 0.f, 0.f};
    f32x4 v1 = {0.f, 0.f, 0.f, 0.f};
#pragma unroll
    for (int sy = 0; sy < 4; ++sy) {
      const f32x4 a = wA[(j + sy) & 3];
      const f32x4 bb = wB[(j + sy) & 3];
      v0 = fma4v(v0, Lw[0][sy], a);
      v0 = fma4v(v0, Hw[0][sy], bb);
      v1 = fma4v(v1, Lw[1][sy], a);
      v1 = fma4v(v1, Hw[1][sy], bb);
    }
    I[buf][2 * sh + 0][c_] = v0;
    I[buf][2 * sh + 1][c_] = v1;
  };

  // Prologue: window rows 0..3, prefetch row 4; p1(0) -> I[0].
  if (doP1) {
#pragma unroll
    for (int m = 0; m < 4; ++m) ldrow(m, wA[m], wB[m]);
    ldrow(4, nA, nB);
    p1(0, 0);
    wA[0] = nA;  // row 4 -> slot 0 (row 0 dead)
    wB[0] = nB;
    ldrow(5, nA, nB);
  }
  LGKM_BARRIER();

  // ---- Pass2 identity: p = t>>7, colf4 = t&127 -> jx = colf4>>1, q ----
  const int pp = t >> 7;
  const int colf4 = t & 127;
  const int jx = colf4 >> 1;
  const int q = colf4 & 1;
  float Lq[4], Hq[4];
#pragma unroll
  for (int s = 0; s < 4; ++s) {
    Lq[s] = q ? Lw[1][s] : Lw[0][s];
    Hq[s] = q ? Hw[1][s] : Hw[0][s];
  }

#pragma unroll
  for (int c = 0; c < RJ; ++c) {
    const int buf = c & 1;

    // ---- Pass2: one output f4: row 2(r0+c)+pp, col f4 2*jc0+colf4 ----
    f32x4 o = {0.f, 0.f, 0.f, 0.f};
#pragma unroll
    for (int s = 0; s < 4; ++s) {
      const int xc = jx + s;  // <= 66, inside halo'd tile
      o = fma4v(o, Lq[s], I[buf][pp][xc]);
      o = fma4v(o, Hq[s], I[buf][2 + pp][xc]);
    }
    const int jy = r0 + c;
    ob[(size_t)(2 * jy + pp) * (2 * N) + 2 * jc0 + colf4] = o;

    if (c < RJ - 1) {
      // ---- Pass1: j-row c+1 (uses window rows c+1..c+4) ----
      if (doP1) {
        p1(c + 1, buf ^ 1);
        // Slide prefetched row c+5 -> slot (c+1)&3; issue row c+6.
        if (c <= RJ - 3) {
          wA[(c + 1) & 3] = nA;
          wB[(c + 1) & 3] = nB;
        }
        if (c <= RJ - 4) ldrow(c + 6, nA, nB);
      }
      LGKM_BARRIER();
    }
  }
}

extern "C" void kernel_launch(void* const* d_in, const int* in_sizes, int n_in,
                              void* d_out, int out_size, void* d_ws,
                              size_t ws_size, hipStream_t stream) {
  const float* x = reinterpret_cast<const float*>(d_in[0]);
  float* out = reinterpret_cast<float*>(d_out);
  const int grid = 64 * (N / RJ) * (N / W);  // 4096 blocks = 8 per CU
  idwt2_sep15_kernel<<<grid, 256, 0, stream>>>(x, out);
}

// Round 17
// 111.955 us; speedup vs baseline: 4.0186x; 4.0186x over previous
//
#include <hip/hip_runtime.h>

// IDWT2D db4, periodized. Input x: [64][256][256][16] f32 (cA|cH|cV|cD x 4ch),
// output: [64][512][512][4] f32.
//
// R16 = R15 with two fixes:
// 1. __launch_bounds__(256,4): R15's (256,8) pinned VGPR=32 -> giant spills
//    (FETCH 992 MB / WRITE 764 MB scratch traffic). Body is ~60 VGPR
//    naturally; <=64 still yields 8 blocks/CU (32-wave cap) WITHOUT spills.
// 2. Column pad CIDX(c)=c+(c>>3) in LDS: R15's layout made even lanes write
//    cols c and c+8 to the same bank (4-way, 2.2e6 conflicts). Padding every
//    8 cols by one f4 separates them for both writes and pass2 reads.
// Structure: block = 16 j-rows x 64 j-cols (+3 x-halo), 256 threads.
// Pass1: 134 threads (67 cols x 2 halves), paired dense 32B/lane loads,
// 4-row register window, prefetch 1 ahead. Pass2: 256 threads = 1 output f4
// (p=t>>7, colf4=t&127), dense stores. 1-row chunks, double-buffered LDS,
// lgkm-only barrier, pk-fma.

#define N 256
#define RJ 16
#define W 64            // output column-pairs per block
#define HC (W + 3)      // intermediate columns incl. halo = 67
#define CIDX(c) ((c) + ((c) >> 3))
#define HCP (HC + (HC >> 3) + 1)  // padded col capacity = 76

typedef float f32x4 __attribute__((ext_vector_type(4)));

// lgkm-only barrier: LDS producer-consumer sync without vmcnt drain.
#define LGKM_BARRIER()                                   \
  do {                                                   \
    asm volatile("s_waitcnt lgkmcnt(0)" ::: "memory");   \
    __builtin_amdgcn_s_barrier();                        \
    asm volatile("" ::: "memory");                       \
  } while (0)

__device__ __forceinline__ f32x4 fma4v(const f32x4 acc, const float s,
                                       const f32x4 a) {
  const f32x4 sv = {s, s, s, s};
  return __builtin_elementwise_fma(a, sv, acc);
}

__global__ __launch_bounds__(256, 4) void idwt2_sep16_kernel(
    const float* __restrict__ x, float* __restrict__ out) {
  constexpr float LO[8] = {
      0.23037781330885523f,  0.7148465705525415f,  0.6308807679295904f,
      -0.02798376941698385f, -0.18703481171888114f, 0.030841381835986965f,
      0.032883011666982945f, -0.010597401784997278f};
  constexpr float HIW[8] = {
      -0.010597401784997278f, -0.032883011666982945f, 0.030841381835986965f,
      0.18703481171888114f,  -0.02798376941698385f,  -0.6308807679295904f,
      0.7148465705525415f,   -0.23037781330885523f};
  const float Lw[2][4] = {{LO[6], LO[4], LO[2], LO[0]},
                          {LO[7], LO[5], LO[3], LO[1]}};
  const float Hw[2][4] = {{HIW[6], HIW[4], HIW[2], HIW[0]},
                          {HIW[7], HIW[5], HIW[3], HIW[1]}};

  // [buf][plane][padded col] f32x4; planes: 0=lo*p0, 1=lo*p1, 2=hi*p0, 3=hi*p1.
  __shared__ f32x4 I[2][4][HCP];

  const int t = threadIdx.x;
  const int bx = blockIdx.x;
  // bx = b*64 + rowgroup*4 + colquarter (colquarter fastest -> halo sharers
  // adjacent in dispatch order for L2/L3 reuse)
  const int cq = bx & 3;
  const int rg = (bx >> 2) & 15;
  const int b = bx >> 6;
  const int r0 = rg * RJ;
  const int jc0 = cq * W;

  const f32x4* xb4 = reinterpret_cast<const f32x4*>(x) + (size_t)b * N * N * 4;
  f32x4* ob = reinterpret_cast<f32x4*>(out) + (size_t)b * (2 * N) * (2 * N);

  // ---- Pass1 identity: slot t = (col c=t>>1, half h=t&1), t < 2*HC ----
  const bool doP1 = t < 2 * HC;
  const int c_ = t >> 1;
  const int sh = t & 1;  // 0: lo from (cA,cH); 1: hi from (cV,cD)
  const int scol = (jc0 + c_) & (N - 1);
  const f32x4* xcolp = xb4 + (size_t)scol * 4 + sh * 2;

  f32x4 wA[4], wB[4], nA, nB;
  auto ldrow = [&](int lr, f32x4& A, f32x4& B) {
    const int gr = (r0 + lr) & (N - 1);
    const f32x4* p = xcolp + (size_t)gr * (N * 4);
    A = p[0];
    B = p[1];
  };

  // y-filter local j-row j into I[buf]; window slot (j+sy)&3 holds row j+sy.
  auto p1 = [&](int j, int buf) {
    f32x4 v0 = {0.f, 0.f, 0.f, 0.f};
    f32x4 v1 = {0.f, 0.f, 0.f, 0.f};
#pragma unroll
    for (int sy = 0; sy < 4; ++sy) {
      const f32x4 a = wA[(j + sy) & 3];
      const f32x4 bb = wB[(j + sy) & 3];
      v0 = fma4v(v0, Lw[0][sy], a);
      v0 = fma4v(v0, Hw[0][sy], bb);
      v1 = fma4v(v1, Lw[1][sy], a);
      v1 = fma4v(v1, Hw[1][sy], bb);
    }
    const int ci = CIDX(c_);
    I[buf][2 * sh + 0][ci] = v0;
    I[buf][2 * sh + 1][ci] = v1;
  };

  // Prologue: window rows 0..3, prefetch row 4; p1(0) -> I[0].
  if (doP1) {
#pragma unroll
    for (int m = 0; m < 4; ++m) ldrow(m, wA[m], wB[m]);
    ldrow(4, nA, nB);
    p1(0, 0);
    wA[0] = nA;  // row 4 -> slot 0 (row 0 dead)
    wB[0] = nB;
    ldrow(5, nA, nB);
  }
  LGKM_BARRIER();

  // ---- Pass2 identity: p = t>>7, colf4 = t&127 -> jx = colf4>>1, q ----
  const int pp = t >> 7;
  const int colf4 = t & 127;
  const int jx = colf4 >> 1;
  const int q = colf4 & 1;
  float Lq[4], Hq[4];
#pragma unroll
  for (int s = 0; s < 4; ++s) {
    Lq[s] = q ? Lw[1][s] : Lw[0][s];
    Hq[s] = q ? Hw[1][s] : Hw[0][s];
  }

#pragma unroll
  for (int c = 0; c < RJ; ++c) {
    const int buf = c & 1;

    // ---- Pass2: one output f4: row 2(r0+c)+pp, col f4 2*jc0+colf4 ----
    f32x4 o = {0.f, 0.f, 0.f, 0.f};
#pragma unroll
    for (int s = 0; s < 4; ++s) {
      const int xc = CIDX(jx + s);  // jx+s <= 66, inside halo'd tile
      o = fma4v(o, Lq[s], I[buf][pp][xc]);
      o = fma4v(o, Hq[s], I[buf][2 + pp][xc]);
    }
    const int jy = r0 + c;
    ob[(size_t)(2 * jy + pp) * (2 * N) + 2 * jc0 + colf4] = o;

    if (c < RJ - 1) {
      // ---- Pass1: j-row c+1 (uses window rows c+1..c+4) ----
      if (doP1) {
        p1(c + 1, buf ^ 1);
        // Slide prefetched row c+5 -> slot (c+1)&3; issue row c+6.
        if (c <= RJ - 3) {
          wA[(c + 1) & 3] = nA;
          wB[(c + 1) & 3] = nB;
        }
        if (c <= RJ - 4) ldrow(c + 6, nA, nB);
      }
      LGKM_BARRIER();
    }
  }
}

extern "C" void kernel_launch(void* const* d_in, const int* in_sizes, int n_in,
                              void* d_out, int out_size, void* d_ws,
                              size_t ws_size, hipStream_t stream) {
  const float* x = reinterpret_cast<const float*>(d_in[0]);
  float* out = reinterpret_cast<float*>(d_out);
  const int grid = 64 * (N / RJ) * (N / W);  // 4096 blocks
  idwt2_sep16_kernel<<<grid, 256, 0, stream>>>(x, out);
}